// Round 3
// baseline (300.115 us; speedup 1.0000x reference)
//
#include <hip/hip_runtime.h>
#include <hip/hip_bf16.h>

#define Bn 4
#define Ln 4096
#define Dn 1024
#define Hn 16
#define KSEL 41

typedef __attribute__((ext_vector_type(8))) short bf16x8;
typedef __attribute__((ext_vector_type(4))) float f32x4;

// ---------- async global->LDS, 16B per lane (dest = wave base + lane*16) ----------
__device__ __forceinline__ void gl2lds16f(const float* g, float* l) {
    __builtin_amdgcn_global_load_lds(
        (const __attribute__((address_space(1))) unsigned int*)(uintptr_t)g,
        (__attribute__((address_space(3))) unsigned int*)(uintptr_t)l,
        16, 0, 0);
}

// ---------- in-register fp32 -> bf16 (hi,lo) split, truncation-based ----------
// hi = trunc_bf16(f) (exact bit mask), lo = trunc_bf16(f - hi). Dropped vs exact:
// lo*lo products (~2^-14 rel) + lo truncation (~2^-14 rel) — negligible at our threshold.
__device__ __forceinline__ void split8(const f32x4& x0, const f32x4& x1,
                                       bf16x8& h, bf16x8& l) {
    union U4 { f32x4 f; unsigned u[4]; };
    U4 a, b; a.f = x0; b.f = x1;
    // hi as fp32 (mask low 16 bits)
    U4 ha, hb;
    #pragma unroll
    for (int i = 0; i < 4; ++i) { ha.u[i] = a.u[i] & 0xFFFF0000u; hb.u[i] = b.u[i] & 0xFFFF0000u; }
    // lo = f - hi (exact)
    U4 la, lb;
    #pragma unroll
    for (int i = 0; i < 4; ++i) { la.f[i] = a.f[i] - ha.f[i]; lb.f[i] = b.f[i] - hb.f[i]; }
    union B8 { bf16x8 v; unsigned u[4]; } hh, ll;
    // pack top halves: word = {elem1.top16, elem0.top16}
    hh.u[0] = __builtin_amdgcn_perm(a.u[1], a.u[0], 0x07060302u);
    hh.u[1] = __builtin_amdgcn_perm(a.u[3], a.u[2], 0x07060302u);
    hh.u[2] = __builtin_amdgcn_perm(b.u[1], b.u[0], 0x07060302u);
    hh.u[3] = __builtin_amdgcn_perm(b.u[3], b.u[2], 0x07060302u);
    ll.u[0] = __builtin_amdgcn_perm(la.u[1], la.u[0], 0x07060302u);
    ll.u[1] = __builtin_amdgcn_perm(la.u[3], la.u[2], 0x07060302u);
    ll.u[2] = __builtin_amdgcn_perm(lb.u[1], lb.u[0], 0x07060302u);
    ll.u[3] = __builtin_amdgcn_perm(lb.u[3], lb.u[2], 0x07060302u);
    h = hh.v; l = ll.v;
}

// ---------------- column sums of q and k ----------------
__global__ void colsum_part(const float* __restrict__ q, const float* __restrict__ k,
                            float* __restrict__ part) {
    int tb = blockIdx.y; int tensor = tb >> 2, b = tb & 3;
    const float4* src = (const float4*)((tensor ? k : q) + (size_t)b * Ln * Dn);
    int d4 = threadIdx.x;
    int t0 = blockIdx.x * 128;
    float sx = 0.f, sy = 0.f, sz = 0.f, sw = 0.f;
    for (int i = 0; i < 128; ++i) {
        float4 v = src[(size_t)(t0 + i) * 256 + d4];
        sx += v.x; sy += v.y; sz += v.z; sw += v.w;
    }
    float4 o; o.x = sx; o.y = sy; o.z = sz; o.w = sw;
    ((float4*)part)[((size_t)tb * 32 + blockIdx.x) * 256 + d4] = o;
}

__global__ void colsum_fin(const float* __restrict__ part, float* __restrict__ sums) {
    int tb = blockIdx.y; int d = blockIdx.x * 256 + threadIdx.x;
    float s = 0.f;
    for (int i = 0; i < 32; ++i) s += part[((size_t)tb * 32 + i) * 1024 + d];
    sums[(size_t)tb * 1024 + d] = s;
}

// ---------------- SQ/SK = colsum @ W^T + L*bias ----------------
__global__ void proj_sums(const float* __restrict__ sums,
                          const float* __restrict__ Wq, const float* __restrict__ bq,
                          const float* __restrict__ Wk, const float* __restrict__ bk,
                          float* __restrict__ SQK) {
    int t = blockIdx.y;
    const float* W    = t ? Wk : Wq;
    const float* bias = t ? bk : bq;
    const float* sv   = sums + (size_t)t * 4 * 1024;
    __shared__ float s_sv[4 * 1024];
    for (int i = threadIdx.x; i < 4 * 1024; i += 256) s_sv[i] = sv[i];
    __syncthreads();
    int wave = threadIdx.x >> 6, lane = threadIdx.x & 63;
    for (int rr = 0; rr < 4; ++rr) {
        int j = blockIdx.x * 16 + rr * 4 + wave;
        float p[4] = {0.f, 0.f, 0.f, 0.f};
        for (int c = 0; c < 4; ++c) {
            float4 wv = *(const float4*)(W + (size_t)j * 1024 + c * 256 + lane * 4);
            #pragma unroll
            for (int b = 0; b < 4; ++b) {
                float4 s = *(const float4*)(s_sv + b * 1024 + c * 256 + lane * 4);
                p[b] += wv.x * s.x + wv.y * s.y + wv.z * s.z + wv.w * s.w;
            }
        }
        #pragma unroll
        for (int b = 0; b < 4; ++b)
            for (int off = 1; off < 64; off <<= 1) p[b] += __shfl_xor(p[b], off);
        if (lane == 0) {
            float bb = bias[j] * (float)Ln;
            #pragma unroll
            for (int b = 0; b < 4; ++b) SQK[((size_t)t * 4 + b) * 1024 + j] = p[b] + bb;
        }
    }
}

// ---------------- fused mean_value + top-41 + softmax ----------------
__global__ void stats_topk(const float* __restrict__ SQK, int* __restrict__ dly,
                           float* __restrict__ wts) {
    __shared__ float s_mv[4][64];
    __shared__ float mab[64];
    __shared__ float selv[4][KSEL];
    int tid = threadIdx.x; int b = tid >> 6, c = tid & 63;
    const float* SQ = SQK; const float* SK = SQK + 4 * 1024;
    float s = 0.f;
    for (int h = 0; h < Hn; ++h)
        s += SQ[(size_t)b * 1024 + h * 64 + c] * SK[(size_t)b * 1024 + h * 64 + c];
    s_mv[b][c] = s * (1.0f / ((float)Hn * (float)Ln));
    __syncthreads();
    if (tid < 64) mab[c] = (s_mv[0][c] + s_mv[1][c] + s_mv[2][c] + s_mv[3][c]) * 0.25f;
    __syncthreads();
    if (tid < 64) {
        float my = mab[c];
        int rank = 0;
        for (int j = 0; j < 64; ++j) {
            float vj = mab[j];
            rank += (vj > my) || (vj == my && j < c);
        }
        if (rank < KSEL) {
            dly[rank] = c;
            selv[0][rank] = s_mv[0][c]; selv[1][rank] = s_mv[1][c];
            selv[2][rank] = s_mv[2][c]; selv[3][rank] = s_mv[3][c];
        }
    }
    __syncthreads();
    if (tid < 4) {
        float mx = -1e30f;
        for (int i = 0; i < KSEL; ++i) mx = fmaxf(mx, selv[tid][i]);
        float ss = 0.f;
        for (int i = 0; i < KSEL; ++i) ss += expf(selv[tid][i] - mx);
        float inv = 1.0f / ss;
        for (int i = 0; i < KSEL; ++i) wts[tid * 64 + i] = expf(selv[tid][i] - mx) * inv;
    }
}

// ---------------- 1024x1024 transpose (Wv -> WvT) ----------------
__global__ void transpose1024(const float* __restrict__ in, float* __restrict__ out) {
    __shared__ float t[32][33];
    int bx = blockIdx.x * 32, by = blockIdx.y * 32;
    int x = threadIdx.x, y0 = threadIdx.y;
    for (int i = 0; i < 32; i += 8) t[y0 + i][x] = in[(size_t)(by + y0 + i) * 1024 + bx + x];
    __syncthreads();
    for (int i = 0; i < 32; i += 8) out[(size_t)(bx + y0 + i) * 1024 + by + x] = t[x][y0 + i];
}

// ---------------- bc = Wo @ bv + bo ----------------
__global__ void bcvec_k(const float* __restrict__ Wo, const float* __restrict__ bv,
                        const float* __restrict__ bo, float* __restrict__ bc) {
    __shared__ float s_bv[1024];
    for (int i = threadIdx.x; i < 1024; i += 256) s_bv[i] = bv[i];
    __syncthreads();
    int wave = threadIdx.x >> 6, lane = threadIdx.x & 63;
    for (int rr = 0; rr < 4; ++rr) {
        int n = blockIdx.x * 16 + rr * 4 + wave;
        float p = 0.f;
        for (int c = 0; c < 4; ++c) {
            float4 wv = *(const float4*)(Wo + (size_t)n * 1024 + c * 256 + lane * 4);
            float4 s  = *(const float4*)(s_bv + c * 256 + lane * 4);
            p += wv.x * s.x + wv.y * s.y + wv.z * s.z + wv.w * s.w;
        }
        for (int off = 1; off < 64; off <<= 1) p += __shfl_xor(p, off);
        if (lane == 0) bc[n] = p + bo[n];
    }
}

// ---------------- fp32 GEMM via MFMA with in-register bf16 split ----------------
// C[m,n] = sum_k A[m,k]*Bt[n,k]; A,Bt staged fp32 via global_load_lds (linear dest,
// XOR-preswizzled source), fragments split to (hi,lo) bf16 in-register, 3 MFMA.
template <int BM>
__global__ __launch_bounds__(256, 2) void gemm_ir(const float* __restrict__ A,
                                                  const float* __restrict__ Bt,
                                                  float* __restrict__ C,
                                                  int N, int K, int nbx) {
    constexpr int FM = BM / 32;              // 16x16 frags per wave dim (wave tile BM/2)
    __shared__ float sA[BM * 32];
    __shared__ float sB[BM * 32];

    int nwg = gridDim.x;
    int bid = blockIdx.x;
    int swz = (bid % 8) * (nwg / 8) + bid / 8;   // nwg % 8 == 0 for our grids
    int by = swz / nbx, bx = swz % nbx;

    const int wave = threadIdx.x >> 6, lane = threadIdx.x & 63;
    const int lrow = lane & 15;
    const int s0 = (lane >> 4) * 2;          // 16B-slot index of fragment k-offset
    const int wr = wave >> 1, wc = wave & 1;
    // staging: lane covers row (chunk*8 + lane/8), global 16B-slot ((lane&7)^(lane/8))
    const int srow8 = lane >> 3;
    const int scol  = ((lane & 7) ^ srow8) * 4;

    f32x4 acc[FM][FM];
    #pragma unroll
    for (int i = 0; i < FM; ++i)
        #pragma unroll
        for (int j = 0; j < FM; ++j) acc[i][j] = (f32x4){0.f, 0.f, 0.f, 0.f};

    for (int k0 = 0; k0 < K; k0 += 32) {
        #pragma unroll
        for (int i = 0; i < BM / 32; ++i) {
            int chunk = wave * (BM / 32) + i;      // 8-row chunk
            int row = chunk * 8 + srow8;
            gl2lds16f(A  + (size_t)(by * BM + row) * K + k0 + scol, sA + chunk * 256);
            gl2lds16f(Bt + (size_t)(bx * BM + row) * K + k0 + scol, sB + chunk * 256);
        }
        __syncthreads();
        bf16x8 bh[FM], bl[FM];
        #pragma unroll
        for (int j = 0; j < FM; ++j) {
            int r = wc * (BM / 2) + j * 16 + lrow;
            int sw = r & 7;
            f32x4 b0 = *(const f32x4*)&sB[r * 32 + (( s0     ) ^ sw) * 4];
            f32x4 b1 = *(const f32x4*)&sB[r * 32 + (((s0 + 1)) ^ sw) * 4];
            split8(b0, b1, bh[j], bl[j]);
        }
        #pragma unroll
        for (int i = 0; i < FM; ++i) {
            int r = wr * (BM / 2) + i * 16 + lrow;
            int sw = r & 7;
            f32x4 a0 = *(const f32x4*)&sA[r * 32 + (( s0     ) ^ sw) * 4];
            f32x4 a1 = *(const f32x4*)&sA[r * 32 + (((s0 + 1)) ^ sw) * 4];
            bf16x8 ah, al;
            split8(a0, a1, ah, al);
            #pragma unroll
            for (int j = 0; j < FM; ++j) {
                acc[i][j] = __builtin_amdgcn_mfma_f32_16x16x32_bf16(ah, bh[j], acc[i][j], 0, 0, 0);
                acc[i][j] = __builtin_amdgcn_mfma_f32_16x16x32_bf16(al, bh[j], acc[i][j], 0, 0, 0);
                acc[i][j] = __builtin_amdgcn_mfma_f32_16x16x32_bf16(ah, bl[j], acc[i][j], 0, 0, 0);
            }
        }
        __syncthreads();
    }
    // C/D layout: row = (lane>>4)*4 + reg, col = lane&15
    #pragma unroll
    for (int i = 0; i < FM; ++i) {
        int r0 = by * BM + wr * (BM / 2) + i * 16 + (lane >> 4) * 4;
        #pragma unroll
        for (int j = 0; j < FM; ++j) {
            int c = bx * BM + wc * (BM / 2) + j * 16 + (lane & 15);
            #pragma unroll
            for (int r = 0; r < 4; ++r)
                C[(size_t)(r0 + r) * N + c] = acc[i][j][r];
        }
    }
}

// ---------------- gather: sliding-window LDS (all delays < 64) ----------------
#define GT 128
#define GC 64
#define GR (GT + 64)
__global__ __launch_bounds__(256) void gather2(const float* __restrict__ O,
                                               const int* __restrict__ dly,
                                               const float* __restrict__ wts,
                                               const float* __restrict__ bc,
                                               float* __restrict__ out) {
    __shared__ float S[GR][GC + 4];
    __shared__ int   s_d[KSEL];
    __shared__ float s_w[KSEL];
    int b = blockIdx.z, c0 = blockIdx.y * GC, t0 = blockIdx.x * GT;
    if (threadIdx.x < KSEL) {
        s_d[threadIdx.x] = dly[threadIdx.x];
        s_w[threadIdx.x] = wts[b * 64 + threadIdx.x];
    }
    const float* Ob = O + (size_t)b * Ln * Dn;
    for (int idx = threadIdx.x; idx < GR * 16; idx += 256) {
        int r = idx >> 4, c4 = idx & 15;
        int gr = (t0 + r) & (Ln - 1);
        *(float4*)&S[r][c4 * 4] = *(const float4*)&Ob[(size_t)gr * Dn + c0 + c4 * 4];
    }
    __syncthreads();
    int c4 = threadIdx.x & 15, tg = threadIdx.x >> 4;
    float4 bias = *(const float4*)&bc[c0 + c4 * 4];
    float4 acc[8];
    #pragma unroll
    for (int r = 0; r < 8; ++r) acc[r] = bias;
    for (int kk = 0; kk < KSEL; ++kk) {
        int d = s_d[kk]; float w = s_w[kk];
        #pragma unroll
        for (int r = 0; r < 8; ++r) {
            float4 v = *(const float4*)&S[tg * 8 + r + d][c4 * 4];
            acc[r].x += w * v.x; acc[r].y += w * v.y;
            acc[r].z += w * v.z; acc[r].w += w * v.w;
        }
    }
    #pragma unroll
    for (int r = 0; r < 8; ++r)
        *(float4*)&out[((size_t)b * Ln + t0 + tg * 8 + r) * Dn + c0 + c4 * 4] = acc[r];
}

extern "C" void kernel_launch(void* const* d_in, const int* in_sizes, int n_in,
                              void* d_out, int out_size, void* d_ws, size_t ws_size,
                              hipStream_t stream) {
    const float* q  = (const float*)d_in[0];
    const float* k  = (const float*)d_in[1];
    const float* v  = (const float*)d_in[2];
    const float* Wq = (const float*)d_in[3];
    const float* bq = (const float*)d_in[4];
    const float* Wk = (const float*)d_in[5];
    const float* bk = (const float*)d_in[6];
    const float* Wv = (const float*)d_in[7];
    const float* bv = (const float*)d_in[8];
    const float* Wo = (const float*)d_in[9];
    const float* bo = (const float*)d_in[10];
    float* out = (float*)d_out;
    float* ws  = (float*)d_ws;

    float* O    = ws;                    // 16777216
    float* Wc   = O + 16777216;          // 1048576
    float* WvT  = Wc + 1048576;          // 1048576
    float* part = WvT + 1048576;         // 262144
    float* sums = part + 262144;         // 8192
    float* SQK  = sums + 8192;           // 8192
    float* wts  = SQK + 8192;            // 256
    float* bc   = wts + 256;             // 1024
    int*   dly  = (int*)(bc + 1024);     // 64

    // correlation-stats chain (cheap, independent)
    hipLaunchKernelGGL(colsum_part, dim3(32, 8), dim3(256), 0, stream, q, k, part);
    hipLaunchKernelGGL(colsum_fin, dim3(4, 8), dim3(256), 0, stream, part, sums);
    hipLaunchKernelGGL(proj_sums, dim3(64, 2), dim3(256), 0, stream, sums, Wq, bq, Wk, bk, SQK);
    hipLaunchKernelGGL(stats_topk, dim3(1), dim3(256), 0, stream, SQK, dly, wts);

    // Wc = Wo @ Wv (NT with Bt = WvT), fp32 in / fp32 out
    hipLaunchKernelGGL(transpose1024, dim3(32, 32), dim3(32, 8), 0, stream, Wv, WvT);
    hipLaunchKernelGGL((gemm_ir<64>), dim3(256), dim3(256), 0, stream,
                       Wo, WvT, Wc, 1024, 1024, 16);
    hipLaunchKernelGGL(bcvec_k, dim3(64), dim3(256), 0, stream, Wo, bv, bo, bc);

    // O = v @ Wc^T  (16384 x 1024 x 1024), fp32 in / fp32 out
    hipLaunchKernelGGL((gemm_ir<128>), dim3(1024), dim3(256), 0, stream,
                       v, Wc, O, 1024, 1024, 8);

    // weighted delay gather + bias
    hipLaunchKernelGGL(gather2, dim3(32, 16, 4), dim3(256), 0, stream, O, dly, wts, bc, out);
}

// Round 4
// 264.055 us; speedup vs baseline: 1.1366x; 1.1366x over previous
//
#include <hip/hip_runtime.h>
#include <hip/hip_bf16.h>

#define Bn 4
#define Ln 4096
#define Dn 1024
#define Hn 16
#define KSEL 41

typedef __attribute__((ext_vector_type(8))) short bf16x8;
typedef __attribute__((ext_vector_type(4))) float f32x4;

// ---------- bf16 helpers (RNE) ----------
__device__ __forceinline__ unsigned short f2bf(float f) {
    unsigned u = __float_as_uint(f);
    unsigned r = (u + 0x7fffu + ((u >> 16) & 1u)) >> 16;
    return (unsigned short)r;
}
__device__ __forceinline__ float bf2f(unsigned short h) {
    return __uint_as_float(((unsigned)h) << 16);
}

// ---------- async global->LDS, 16B per lane ----------
__device__ __forceinline__ void gl2lds16(const unsigned short* g, unsigned short* l) {
    __builtin_amdgcn_global_load_lds(
        (const __attribute__((address_space(1))) unsigned int*)(uintptr_t)g,
        (__attribute__((address_space(3))) unsigned int*)(uintptr_t)l,
        16, 0, 0);
}

// ---------------- column sums of q and k ----------------
__global__ void colsum_part(const float* __restrict__ q, const float* __restrict__ k,
                            float* __restrict__ part) {
    int tb = blockIdx.y; int tensor = tb >> 2, b = tb & 3;
    const float4* src = (const float4*)((tensor ? k : q) + (size_t)b * Ln * Dn);
    int d4 = threadIdx.x;
    int t0 = blockIdx.x * 128;
    float sx = 0.f, sy = 0.f, sz = 0.f, sw = 0.f;
    for (int i = 0; i < 128; ++i) {
        float4 v = src[(size_t)(t0 + i) * 256 + d4];
        sx += v.x; sy += v.y; sz += v.z; sw += v.w;
    }
    float4 o; o.x = sx; o.y = sy; o.z = sz; o.w = sw;
    ((float4*)part)[((size_t)tb * 32 + blockIdx.x) * 256 + d4] = o;
}

__global__ void colsum_fin(const float* __restrict__ part, float* __restrict__ sums) {
    int tb = blockIdx.y; int d = blockIdx.x * 256 + threadIdx.x;
    float s = 0.f;
    for (int i = 0; i < 32; ++i) s += part[((size_t)tb * 32 + i) * 1024 + d];
    sums[(size_t)tb * 1024 + d] = s;
}

// ---------------- SQ/SK = colsum @ W^T + L*bias ----------------
__global__ void proj_sums(const float* __restrict__ sums,
                          const float* __restrict__ Wq, const float* __restrict__ bq,
                          const float* __restrict__ Wk, const float* __restrict__ bk,
                          float* __restrict__ SQK) {
    int t = blockIdx.y;
    const float* W    = t ? Wk : Wq;
    const float* bias = t ? bk : bq;
    const float* sv   = sums + (size_t)t * 4 * 1024;
    __shared__ float s_sv[4 * 1024];
    for (int i = threadIdx.x; i < 4 * 1024; i += 256) s_sv[i] = sv[i];
    __syncthreads();
    int wave = threadIdx.x >> 6, lane = threadIdx.x & 63;
    for (int rr = 0; rr < 4; ++rr) {
        int j = blockIdx.x * 16 + rr * 4 + wave;
        float p[4] = {0.f, 0.f, 0.f, 0.f};
        for (int c = 0; c < 4; ++c) {
            float4 wv = *(const float4*)(W + (size_t)j * 1024 + c * 256 + lane * 4);
            #pragma unroll
            for (int b = 0; b < 4; ++b) {
                float4 s = *(const float4*)(s_sv + b * 1024 + c * 256 + lane * 4);
                p[b] += wv.x * s.x + wv.y * s.y + wv.z * s.z + wv.w * s.w;
            }
        }
        #pragma unroll
        for (int b = 0; b < 4; ++b)
            for (int off = 1; off < 64; off <<= 1) p[b] += __shfl_xor(p[b], off);
        if (lane == 0) {
            float bb = bias[j] * (float)Ln;
            #pragma unroll
            for (int b = 0; b < 4; ++b) SQK[((size_t)t * 4 + b) * 1024 + j] = p[b] + bb;
        }
    }
}

// ---------------- fused mean_value + top-41 + softmax ----------------
__global__ void stats_topk(const float* __restrict__ SQK, int* __restrict__ dly,
                           float* __restrict__ wts) {
    __shared__ float s_mv[4][64];
    __shared__ float mab[64];
    __shared__ float selv[4][KSEL];
    int tid = threadIdx.x; int b = tid >> 6, c = tid & 63;
    const float* SQ = SQK; const float* SK = SQK + 4 * 1024;
    float s = 0.f;
    for (int h = 0; h < Hn; ++h)
        s += SQ[(size_t)b * 1024 + h * 64 + c] * SK[(size_t)b * 1024 + h * 64 + c];
    s_mv[b][c] = s * (1.0f / ((float)Hn * (float)Ln));
    __syncthreads();
    if (tid < 64) mab[c] = (s_mv[0][c] + s_mv[1][c] + s_mv[2][c] + s_mv[3][c]) * 0.25f;
    __syncthreads();
    if (tid < 64) {
        float my = mab[c];
        int rank = 0;
        for (int j = 0; j < 64; ++j) {
            float vj = mab[j];
            rank += (vj > my) || (vj == my && j < c);
        }
        if (rank < KSEL) {
            dly[rank] = c;
            selv[0][rank] = s_mv[0][c]; selv[1][rank] = s_mv[1][c];
            selv[2][rank] = s_mv[2][c]; selv[3][rank] = s_mv[3][c];
        }
    }
    __syncthreads();
    if (tid < 4) {
        float mx = -1e30f;
        for (int i = 0; i < KSEL; ++i) mx = fmaxf(mx, selv[tid][i]);
        float ss = 0.f;
        for (int i = 0; i < KSEL; ++i) ss += expf(selv[tid][i] - mx);
        float inv = 1.0f / ss;
        for (int i = 0; i < KSEL; ++i) wts[tid * 64 + i] = expf(selv[tid][i] - mx) * inv;
    }
}

// ---------------- fp32 -> (hi,lo) bf16 split (for Wo) ----------------
__global__ void split_fp32(const float* __restrict__ x, unsigned short* __restrict__ hi,
                           unsigned short* __restrict__ lo, int n4) {
    int i = blockIdx.x * 256 + threadIdx.x;
    if (i >= n4) return;
    float4 v = ((const float4*)x)[i];
    ushort4 h, l;
    h.x = f2bf(v.x); l.x = f2bf(v.x - bf2f(h.x));
    h.y = f2bf(v.y); l.y = f2bf(v.y - bf2f(h.y));
    h.z = f2bf(v.z); l.z = f2bf(v.z - bf2f(h.z));
    h.w = f2bf(v.w); l.w = f2bf(v.w - bf2f(h.w));
    ((ushort4*)hi)[i] = h; ((ushort4*)lo)[i] = l;
}

// ---------------- 1024x1024 transpose + split (for Wv) ----------------
__global__ void transpose_split(const float* __restrict__ in, unsigned short* __restrict__ oh,
                                unsigned short* __restrict__ ol) {
    __shared__ float t[32][33];
    int bx = blockIdx.x * 32, by = blockIdx.y * 32;
    int x = threadIdx.x, y0 = threadIdx.y;
    for (int i = 0; i < 32; i += 8) t[y0 + i][x] = in[(size_t)(by + y0 + i) * 1024 + bx + x];
    __syncthreads();
    for (int i = 0; i < 32; i += 8) {
        float v = t[x][y0 + i];
        unsigned short h = f2bf(v);
        unsigned short l = f2bf(v - bf2f(h));
        size_t idx = (size_t)(bx + y0 + i) * 1024 + by + x;
        oh[idx] = h; ol[idx] = l;
    }
}

// ---------------- bc = Wo @ bv + bo ----------------
__global__ void bcvec_k(const float* __restrict__ Wo, const float* __restrict__ bv,
                        const float* __restrict__ bo, float* __restrict__ bc) {
    __shared__ float s_bv[1024];
    for (int i = threadIdx.x; i < 1024; i += 256) s_bv[i] = bv[i];
    __syncthreads();
    int wave = threadIdx.x >> 6, lane = threadIdx.x & 63;
    for (int rr = 0; rr < 4; ++rr) {
        int n = blockIdx.x * 16 + rr * 4 + wave;
        float p = 0.f;
        for (int c = 0; c < 4; ++c) {
            float4 wv = *(const float4*)(Wo + (size_t)n * 1024 + c * 256 + lane * 4);
            float4 s  = *(const float4*)(s_bv + c * 256 + lane * 4);
            p += wv.x * s.x + wv.y * s.y + wv.z * s.z + wv.w * s.w;
        }
        for (int off = 1; off < 64; off <<= 1) p += __shfl_xor(p, off);
        if (lane == 0) bc[n] = p + bo[n];
    }
}

// ---------------- gather on v + bf16 hi/lo split ----------------
// Vagg[b,t,c] = sum_k w[b,k]*v[b,(t+d_k)%L,c]; write as bf16 hi/lo pair.
#define GT 128
#define GC 64
#define GR (GT + 64)
__global__ __launch_bounds__(256) void gather_v(const float* __restrict__ v,
                                                const int* __restrict__ dly,
                                                const float* __restrict__ wts,
                                                unsigned short* __restrict__ Vhi,
                                                unsigned short* __restrict__ Vlo) {
    __shared__ float S[GR][GC + 4];
    __shared__ int   s_d[KSEL];
    __shared__ float s_w[KSEL];
    int b = blockIdx.z, c0 = blockIdx.y * GC, t0 = blockIdx.x * GT;
    if (threadIdx.x < KSEL) {
        s_d[threadIdx.x] = dly[threadIdx.x];
        s_w[threadIdx.x] = wts[b * 64 + threadIdx.x];
    }
    const float* Vb = v + (size_t)b * Ln * Dn;
    for (int idx = threadIdx.x; idx < GR * 16; idx += 256) {
        int r = idx >> 4, c4 = idx & 15;
        int gr = (t0 + r) & (Ln - 1);
        *(float4*)&S[r][c4 * 4] = *(const float4*)&Vb[(size_t)gr * Dn + c0 + c4 * 4];
    }
    __syncthreads();
    int c4 = threadIdx.x & 15, tg = threadIdx.x >> 4;   // 16 groups x 8 t-rows
    float4 acc[8];
    #pragma unroll
    for (int r = 0; r < 8; ++r) acc[r] = make_float4(0.f, 0.f, 0.f, 0.f);
    for (int kk = 0; kk < KSEL; ++kk) {
        int d = s_d[kk]; float w = s_w[kk];
        #pragma unroll
        for (int r = 0; r < 8; ++r) {
            float4 x = *(const float4*)&S[tg * 8 + r + d][c4 * 4];
            acc[r].x += w * x.x; acc[r].y += w * x.y;
            acc[r].z += w * x.z; acc[r].w += w * x.w;
        }
    }
    #pragma unroll
    for (int r = 0; r < 8; ++r) {
        size_t idx = ((size_t)b * Ln + t0 + tg * 8 + r) * Dn + c0 + c4 * 4;
        ushort4 h, l;
        h.x = f2bf(acc[r].x); l.x = f2bf(acc[r].x - bf2f(h.x));
        h.y = f2bf(acc[r].y); l.y = f2bf(acc[r].y - bf2f(h.y));
        h.z = f2bf(acc[r].z); l.z = f2bf(acc[r].z - bf2f(h.z));
        h.w = f2bf(acc[r].w); l.w = f2bf(acc[r].w - bf2f(h.w));
        *(ushort4*)&Vhi[idx] = h;
        *(ushort4*)&Vlo[idx] = l;
    }
}

// ---------------- bf16 split-GEMM via MFMA (round-2 proven structure) ----------------
// C[m,n] = sum_k (Ah+Al)[m,k]*(Bh+Bl)[n,k], dropping Al*Bl. Optional fused bias.
template <int BM, bool SPLIT_OUT>
__global__ __launch_bounds__(256, 2) void gemm_sp(
    const unsigned short* __restrict__ Ah, const unsigned short* __restrict__ Al,
    const unsigned short* __restrict__ Bh, const unsigned short* __restrict__ Bl,
    float* __restrict__ C, unsigned short* __restrict__ Ch, unsigned short* __restrict__ Cl,
    const float* __restrict__ bias,
    int N, int K, int nbx) {
    constexpr int FM = BM / 32;
    __shared__ unsigned short sAh[BM * 32];
    __shared__ unsigned short sAl[BM * 32];
    __shared__ unsigned short sBh[BM * 32];
    __shared__ unsigned short sBl[BM * 32];

    int nwg = gridDim.x;
    int bid = blockIdx.x;
    int swz = (bid % 8) * (nwg / 8) + bid / 8;   // nwg % 8 == 0 for our grids
    int by = swz / nbx, bx = swz % nbx;

    const int wave = threadIdx.x >> 6, lane = threadIdx.x & 63;
    const int lrow = lane & 15, lk = (lane >> 4) * 8;
    const int wr = wave >> 1, wc = wave & 1;

    f32x4 acc[FM][FM];
    #pragma unroll
    for (int i = 0; i < FM; ++i)
        #pragma unroll
        for (int j = 0; j < FM; ++j) acc[i][j] = (f32x4){0.f, 0.f, 0.f, 0.f};

    const int srow = lane >> 2;
    const int skq  = (lane & 3) * 8;

    for (int k0 = 0; k0 < K; k0 += 32) {
        #pragma unroll
        for (int j = 0; j < BM / 64; ++j) {
            int chunk = j * 4 + wave;
            int row = chunk * 16 + srow;
            size_t goffA = (size_t)((by * BM) + row) * K + k0 + skq;
            size_t goffB = (size_t)((bx * BM) + row) * K + k0 + skq;
            gl2lds16(Ah + goffA, sAh + chunk * 512);
            gl2lds16(Al + goffA, sAl + chunk * 512);
            gl2lds16(Bh + goffB, sBh + chunk * 512);
            gl2lds16(Bl + goffB, sBl + chunk * 512);
        }
        __syncthreads();
        bf16x8 bh[FM], bl[FM];
        #pragma unroll
        for (int j = 0; j < FM; ++j) {
            int r = wc * (BM / 2) + j * 16 + lrow;
            bh[j] = *(const bf16x8*)&sBh[r * 32 + lk];
            bl[j] = *(const bf16x8*)&sBl[r * 32 + lk];
        }
        #pragma unroll
        for (int i = 0; i < FM; ++i) {
            int r = wr * (BM / 2) + i * 16 + lrow;
            bf16x8 ah = *(const bf16x8*)&sAh[r * 32 + lk];
            bf16x8 al = *(const bf16x8*)&sAl[r * 32 + lk];
            #pragma unroll
            for (int j = 0; j < FM; ++j) {
                acc[i][j] = __builtin_amdgcn_mfma_f32_16x16x32_bf16(ah, bh[j], acc[i][j], 0, 0, 0);
                acc[i][j] = __builtin_amdgcn_mfma_f32_16x16x32_bf16(al, bh[j], acc[i][j], 0, 0, 0);
                acc[i][j] = __builtin_amdgcn_mfma_f32_16x16x32_bf16(ah, bl[j], acc[i][j], 0, 0, 0);
            }
        }
        __syncthreads();
    }
    // C/D layout: row = (lane>>4)*4 + reg, col = lane&15
    #pragma unroll
    for (int i = 0; i < FM; ++i) {
        int r0 = by * BM + wr * (BM / 2) + i * 16 + (lane >> 4) * 4;
        #pragma unroll
        for (int j = 0; j < FM; ++j) {
            int c = bx * BM + wc * (BM / 2) + j * 16 + (lane & 15);
            float bb = SPLIT_OUT ? 0.f : bias[c];
            #pragma unroll
            for (int r = 0; r < 4; ++r) {
                float v = acc[i][j][r];
                size_t idx = (size_t)(r0 + r) * N + c;
                if (SPLIT_OUT) {
                    unsigned short h = f2bf(v);
                    Ch[idx] = h; Cl[idx] = f2bf(v - bf2f(h));
                } else {
                    C[idx] = v + bb;
                }
            }
        }
    }
}

extern "C" void kernel_launch(void* const* d_in, const int* in_sizes, int n_in,
                              void* d_out, int out_size, void* d_ws, size_t ws_size,
                              hipStream_t stream) {
    const float* q  = (const float*)d_in[0];
    const float* k  = (const float*)d_in[1];
    const float* v  = (const float*)d_in[2];
    const float* Wq = (const float*)d_in[3];
    const float* bq = (const float*)d_in[4];
    const float* Wk = (const float*)d_in[5];
    const float* bk = (const float*)d_in[6];
    const float* Wv = (const float*)d_in[7];
    const float* bv = (const float*)d_in[8];
    const float* Wo = (const float*)d_in[9];
    const float* bo = (const float*)d_in[10];
    float* out = (float*)d_out;
    float* ws  = (float*)d_ws;

    unsigned short* Vhi   = (unsigned short*)ws;        // 16777216 ushort
    unsigned short* Vlo   = Vhi + 16777216;             // 16777216
    unsigned short* Wohi  = Vlo + 16777216;             // 1048576
    unsigned short* Wolo  = Wohi + 1048576;
    unsigned short* WvThi = Wolo + 1048576;
    unsigned short* WvTlo = WvThi + 1048576;
    unsigned short* Wchi  = WvTlo + 1048576;
    unsigned short* Wclo  = Wchi + 1048576;
    float* part = (float*)(Wclo + 1048576);             // 262144 floats
    float* sums = part + 262144;                        // 8192
    float* SQK  = sums + 8192;                          // 8192
    float* wts  = SQK + 8192;                           // 256
    float* bc   = wts + 256;                            // 1024
    int*   dly  = (int*)(bc + 1024);                    // 64

    // correlation-stats chain -> dly, wts
    hipLaunchKernelGGL(colsum_part, dim3(32, 8), dim3(256), 0, stream, q, k, part);
    hipLaunchKernelGGL(colsum_fin, dim3(4, 8), dim3(256), 0, stream, part, sums);
    hipLaunchKernelGGL(proj_sums, dim3(64, 2), dim3(256), 0, stream, sums, Wq, bq, Wk, bk, SQK);
    hipLaunchKernelGGL(stats_topk, dim3(1), dim3(256), 0, stream, SQK, dly, wts);

    // weight prep: Wc = Wo @ Wv (split-bf16 out), bc = Wo@bv + bo
    hipLaunchKernelGGL(split_fp32, dim3(1024), dim3(256), 0, stream, Wo, Wohi, Wolo, 262144);
    hipLaunchKernelGGL(transpose_split, dim3(32, 32), dim3(32, 8), 0, stream, Wv, WvThi, WvTlo);
    hipLaunchKernelGGL((gemm_sp<64, true>), dim3(256), dim3(256), 0, stream,
                       Wohi, Wolo, WvThi, WvTlo, (float*)nullptr, Wchi, Wclo,
                       (const float*)nullptr, 1024, 1024, 16);
    hipLaunchKernelGGL(bcvec_k, dim3(64), dim3(256), 0, stream, Wo, bv, bo, bc);

    // gather on v (commutes with the output projection) + bf16 split
    hipLaunchKernelGGL(gather_v, dim3(32, 16, 4), dim3(256), 0, stream, v, dly, wts, Vhi, Vlo);

    // out = Vagg @ Wc^T + bc  (16384 x 1024 x 1024), fused bias
    hipLaunchKernelGGL((gemm_sp<128, false>), dim3(1024), dim3(256), 0, stream,
                       Vhi, Vlo, Wchi, Wclo, out, (unsigned short*)nullptr,
                       (unsigned short*)nullptr, bc, 1024, 1024, 8);
}

// Round 5
// 178.842 us; speedup vs baseline: 1.6781x; 1.4765x over previous
//
#include <hip/hip_runtime.h>
#include <hip/hip_bf16.h>

#define Bn 4
#define Ln 4096
#define Dn 1024
#define Hn 16
#define KSEL 41

typedef __attribute__((ext_vector_type(8))) _Float16 f16x8;
typedef __attribute__((ext_vector_type(4))) float f32x4;

// ---------- f32 -> f16 bits (RNE via hardware cvt) ----------
__device__ __forceinline__ unsigned short f2h(float f) {
    union { _Float16 h; unsigned short u; } c;
    c.h = (_Float16)f;
    return c.u;
}

// ---------- async global->LDS, 16B per lane ----------
__device__ __forceinline__ void gl2lds16(const unsigned short* g, unsigned short* l) {
    __builtin_amdgcn_global_load_lds(
        (const __attribute__((address_space(1))) unsigned int*)(uintptr_t)g,
        (__attribute__((address_space(3))) unsigned int*)(uintptr_t)l,
        16, 0, 0);
}

// ---------------- column sums of q and k ----------------
__global__ void colsum_part(const float* __restrict__ q, const float* __restrict__ k,
                            float* __restrict__ part) {
    int tb = blockIdx.y; int tensor = tb >> 2, b = tb & 3;
    const float4* src = (const float4*)((tensor ? k : q) + (size_t)b * Ln * Dn);
    int d4 = threadIdx.x;
    int t0 = blockIdx.x * 128;
    float sx = 0.f, sy = 0.f, sz = 0.f, sw = 0.f;
    for (int i = 0; i < 128; ++i) {
        float4 v = src[(size_t)(t0 + i) * 256 + d4];
        sx += v.x; sy += v.y; sz += v.z; sw += v.w;
    }
    float4 o; o.x = sx; o.y = sy; o.z = sz; o.w = sw;
    ((float4*)part)[((size_t)tb * 32 + blockIdx.x) * 256 + d4] = o;
}

__global__ void colsum_fin(const float* __restrict__ part, float* __restrict__ sums) {
    int tb = blockIdx.y; int d = blockIdx.x * 256 + threadIdx.x;
    float s = 0.f;
    for (int i = 0; i < 32; ++i) s += part[((size_t)tb * 32 + i) * 1024 + d];
    sums[(size_t)tb * 1024 + d] = s;
}

// ---------------- SQ/SK = colsum @ W^T + L*bias ----------------
__global__ void proj_sums(const float* __restrict__ sums,
                          const float* __restrict__ Wq, const float* __restrict__ bq,
                          const float* __restrict__ Wk, const float* __restrict__ bk,
                          float* __restrict__ SQK) {
    int t = blockIdx.y;
    const float* W    = t ? Wk : Wq;
    const float* bias = t ? bk : bq;
    const float* sv   = sums + (size_t)t * 4 * 1024;
    __shared__ float s_sv[4 * 1024];
    for (int i = threadIdx.x; i < 4 * 1024; i += 256) s_sv[i] = sv[i];
    __syncthreads();
    int wave = threadIdx.x >> 6, lane = threadIdx.x & 63;
    for (int rr = 0; rr < 4; ++rr) {
        int j = blockIdx.x * 16 + rr * 4 + wave;
        float p[4] = {0.f, 0.f, 0.f, 0.f};
        for (int c = 0; c < 4; ++c) {
            float4 wv = *(const float4*)(W + (size_t)j * 1024 + c * 256 + lane * 4);
            #pragma unroll
            for (int b = 0; b < 4; ++b) {
                float4 s = *(const float4*)(s_sv + b * 1024 + c * 256 + lane * 4);
                p[b] += wv.x * s.x + wv.y * s.y + wv.z * s.z + wv.w * s.w;
            }
        }
        #pragma unroll
        for (int b = 0; b < 4; ++b)
            for (int off = 1; off < 64; off <<= 1) p[b] += __shfl_xor(p[b], off);
        if (lane == 0) {
            float bb = bias[j] * (float)Ln;
            #pragma unroll
            for (int b = 0; b < 4; ++b) SQK[((size_t)t * 4 + b) * 1024 + j] = p[b] + bb;
        }
    }
}

// ---------------- fused mean_value + top-41 + softmax ----------------
__global__ void stats_topk(const float* __restrict__ SQK, int* __restrict__ dly,
                           float* __restrict__ wts) {
    __shared__ float s_mv[4][64];
    __shared__ float mab[64];
    __shared__ float selv[4][KSEL];
    int tid = threadIdx.x; int b = tid >> 6, c = tid & 63;
    const float* SQ = SQK; const float* SK = SQK + 4 * 1024;
    float s = 0.f;
    for (int h = 0; h < Hn; ++h)
        s += SQ[(size_t)b * 1024 + h * 64 + c] * SK[(size_t)b * 1024 + h * 64 + c];
    s_mv[b][c] = s * (1.0f / ((float)Hn * (float)Ln));
    __syncthreads();
    if (tid < 64) mab[c] = (s_mv[0][c] + s_mv[1][c] + s_mv[2][c] + s_mv[3][c]) * 0.25f;
    __syncthreads();
    if (tid < 64) {
        float my = mab[c];
        int rank = 0;
        for (int j = 0; j < 64; ++j) {
            float vj = mab[j];
            rank += (vj > my) || (vj == my && j < c);
        }
        if (rank < KSEL) {
            dly[rank] = c;
            selv[0][rank] = s_mv[0][c]; selv[1][rank] = s_mv[1][c];
            selv[2][rank] = s_mv[2][c]; selv[3][rank] = s_mv[3][c];
        }
    }
    __syncthreads();
    if (tid < 4) {
        float mx = -1e30f;
        for (int i = 0; i < KSEL; ++i) mx = fmaxf(mx, selv[tid][i]);
        float ss = 0.f;
        for (int i = 0; i < KSEL; ++i) ss += expf(selv[tid][i] - mx);
        float inv = 1.0f / ss;
        for (int i = 0; i < KSEL; ++i) wts[tid * 64 + i] = expf(selv[tid][i] - mx) * inv;
    }
}

// ---------------- weight prep: z=0 Wo->f16 straight; z=1 Wv->transpose->f16 ----------------
__global__ void prep_w(const float* __restrict__ Wo, const float* __restrict__ Wv,
                       unsigned short* __restrict__ Wof, unsigned short* __restrict__ WvTf) {
    int bx = blockIdx.x * 32, by = blockIdx.y * 32;
    int x = threadIdx.x, y0 = threadIdx.y;
    if (blockIdx.z == 0) {
        for (int i = 0; i < 32; i += 8) {
            size_t idx = (size_t)(by + y0 + i) * 1024 + bx + x;
            Wof[idx] = f2h(Wo[idx]);
        }
    } else {
        __shared__ float t[32][33];
        for (int i = 0; i < 32; i += 8)
            t[y0 + i][x] = Wv[(size_t)(by + y0 + i) * 1024 + bx + x];
        __syncthreads();
        for (int i = 0; i < 32; i += 8)
            WvTf[(size_t)(bx + y0 + i) * 1024 + by + x] = f2h(t[x][y0 + i]);
    }
}

// ---------------- bc = Wo @ bv + bo (fp32) ----------------
__global__ void bcvec_k(const float* __restrict__ Wo, const float* __restrict__ bv,
                        const float* __restrict__ bo, float* __restrict__ bc) {
    __shared__ float s_bv[1024];
    for (int i = threadIdx.x; i < 1024; i += 256) s_bv[i] = bv[i];
    __syncthreads();
    int wave = threadIdx.x >> 6, lane = threadIdx.x & 63;
    for (int rr = 0; rr < 4; ++rr) {
        int n = blockIdx.x * 16 + rr * 4 + wave;
        float p = 0.f;
        for (int c = 0; c < 4; ++c) {
            float4 wv = *(const float4*)(Wo + (size_t)n * 1024 + c * 256 + lane * 4);
            float4 s  = *(const float4*)(s_bv + c * 256 + lane * 4);
            p += wv.x * s.x + wv.y * s.y + wv.z * s.z + wv.w * s.w;
        }
        for (int off = 1; off < 64; off <<= 1) p += __shfl_xor(p, off);
        if (lane == 0) bc[n] = p + bo[n];
    }
}

// ---------------- gather on v -> f16 ----------------
// Vf[b,t,c] = f16( sum_k w[b,k]*v[b,(t+d_k)%L,c] )
#define GT 128
#define GC 64
#define GR (GT + 64)
__global__ __launch_bounds__(256) void gather_v(const float* __restrict__ v,
                                                const int* __restrict__ dly,
                                                const float* __restrict__ wts,
                                                unsigned short* __restrict__ Vf) {
    __shared__ float S[GR][GC + 4];
    __shared__ int   s_d[KSEL];
    __shared__ float s_w[KSEL];
    int b = blockIdx.z, c0 = blockIdx.y * GC, t0 = blockIdx.x * GT;
    if (threadIdx.x < KSEL) {
        s_d[threadIdx.x] = dly[threadIdx.x];
        s_w[threadIdx.x] = wts[b * 64 + threadIdx.x];
    }
    const float* Vb = v + (size_t)b * Ln * Dn;
    for (int idx = threadIdx.x; idx < GR * 16; idx += 256) {
        int r = idx >> 4, c4 = idx & 15;
        int gr = (t0 + r) & (Ln - 1);
        *(float4*)&S[r][c4 * 4] = *(const float4*)&Vb[(size_t)gr * Dn + c0 + c4 * 4];
    }
    __syncthreads();
    int c4 = threadIdx.x & 15, tg = threadIdx.x >> 4;   // 16 groups x 8 t-rows
    float4 acc[8];
    #pragma unroll
    for (int r = 0; r < 8; ++r) acc[r] = make_float4(0.f, 0.f, 0.f, 0.f);
    for (int kk = 0; kk < KSEL; ++kk) {
        int d = s_d[kk]; float w = s_w[kk];
        #pragma unroll
        for (int r = 0; r < 8; ++r) {
            float4 x = *(const float4*)&S[tg * 8 + r + d][c4 * 4];
            acc[r].x += w * x.x; acc[r].y += w * x.y;
            acc[r].z += w * x.z; acc[r].w += w * x.w;
        }
    }
    #pragma unroll
    for (int r = 0; r < 8; ++r) {
        size_t idx = ((size_t)b * Ln + t0 + tg * 8 + r) * Dn + c0 + c4 * 4;
        ushort4 o;
        o.x = f2h(acc[r].x); o.y = f2h(acc[r].y);
        o.z = f2h(acc[r].z); o.w = f2h(acc[r].w);
        *(ushort4*)&Vf[idx] = o;
    }
}

// ---------------- f16 single-MFMA NT GEMM (m97 structure) ----------------
// C[m,n] = sum_k A[m,k]*Bt[n,k]; A,Bt f16 row-major. OUT_F16: write f16 bits;
// else fp32 with fused bias.
template <int BM, bool OUT_F16>
__global__ __launch_bounds__(256, 2) void gemm_f16(
    const unsigned short* __restrict__ A, const unsigned short* __restrict__ Bt,
    float* __restrict__ C, unsigned short* __restrict__ Cf,
    const float* __restrict__ bias,
    int N, int K, int nbx) {
    constexpr int FM = BM / 32;
    __shared__ unsigned short sA[BM * 32];
    __shared__ unsigned short sB[BM * 32];

    int nwg = gridDim.x;
    int bid = blockIdx.x;
    int swz = (bid % 8) * (nwg / 8) + bid / 8;   // nwg % 8 == 0 for our grids
    int by = swz / nbx, bx = swz % nbx;

    const int wave = threadIdx.x >> 6, lane = threadIdx.x & 63;
    const int lrow = lane & 15, lk = (lane >> 4) * 8;
    const int wr = wave >> 1, wc = wave & 1;

    f32x4 acc[FM][FM];
    #pragma unroll
    for (int i = 0; i < FM; ++i)
        #pragma unroll
        for (int j = 0; j < FM; ++j) acc[i][j] = (f32x4){0.f, 0.f, 0.f, 0.f};

    const int srow = lane >> 2;          // 16 rows per 1KB chunk
    const int skq  = (lane & 3) * 8;     // 8 f16 = 16B per lane

    for (int k0 = 0; k0 < K; k0 += 32) {
        #pragma unroll
        for (int j = 0; j < BM / 64; ++j) {
            int chunk = j * 4 + wave;
            int row = chunk * 16 + srow;
            gl2lds16(A  + (size_t)((by * BM) + row) * K + k0 + skq, sA + chunk * 512);
            gl2lds16(Bt + (size_t)((bx * BM) + row) * K + k0 + skq, sB + chunk * 512);
        }
        __syncthreads();
        f16x8 bfrag[FM];
        #pragma unroll
        for (int j = 0; j < FM; ++j) {
            int r = wc * (BM / 2) + j * 16 + lrow;
            bfrag[j] = *(const f16x8*)&sB[r * 32 + lk];
        }
        #pragma unroll
        for (int i = 0; i < FM; ++i) {
            int r = wr * (BM / 2) + i * 16 + lrow;
            f16x8 afrag = *(const f16x8*)&sA[r * 32 + lk];
            #pragma unroll
            for (int j = 0; j < FM; ++j)
                acc[i][j] = __builtin_amdgcn_mfma_f32_16x16x32_f16(afrag, bfrag[j], acc[i][j], 0, 0, 0);
        }
        __syncthreads();
    }
    // C/D layout: row = (lane>>4)*4 + reg, col = lane&15
    #pragma unroll
    for (int i = 0; i < FM; ++i) {
        int r0 = by * BM + wr * (BM / 2) + i * 16 + (lane >> 4) * 4;
        #pragma unroll
        for (int j = 0; j < FM; ++j) {
            int c = bx * BM + wc * (BM / 2) + j * 16 + (lane & 15);
            float bb = OUT_F16 ? 0.f : bias[c];
            #pragma unroll
            for (int r = 0; r < 4; ++r) {
                size_t idx = (size_t)(r0 + r) * N + c;
                if (OUT_F16) Cf[idx] = f2h(acc[i][j][r]);
                else         C[idx]  = acc[i][j][r] + bb;
            }
        }
    }
}

extern "C" void kernel_launch(void* const* d_in, const int* in_sizes, int n_in,
                              void* d_out, int out_size, void* d_ws, size_t ws_size,
                              hipStream_t stream) {
    const float* q  = (const float*)d_in[0];
    const float* k  = (const float*)d_in[1];
    const float* v  = (const float*)d_in[2];
    const float* Wq = (const float*)d_in[3];
    const float* bq = (const float*)d_in[4];
    const float* Wk = (const float*)d_in[5];
    const float* bk = (const float*)d_in[6];
    const float* Wv = (const float*)d_in[7];
    const float* bv = (const float*)d_in[8];
    const float* Wo = (const float*)d_in[9];
    const float* bo = (const float*)d_in[10];
    float* out = (float*)d_out;
    float* ws  = (float*)d_ws;

    unsigned short* Vf    = (unsigned short*)ws;        // 16777216 ushort (32 MB)
    unsigned short* Wof   = Vf + 16777216;              // 1048576
    unsigned short* WvTf  = Wof + 1048576;              // 1048576
    unsigned short* Wcf   = WvTf + 1048576;             // 1048576
    float* part = (float*)(Wcf + 1048576);              // 262144 floats
    float* sums = part + 262144;                        // 8192
    float* SQK  = sums + 8192;                          // 8192
    float* wts  = SQK + 8192;                           // 256
    float* bc   = wts + 256;                            // 1024
    int*   dly  = (int*)(bc + 1024);                    // 64

    // correlation-stats chain -> dly, wts
    hipLaunchKernelGGL(colsum_part, dim3(32, 8), dim3(256), 0, stream, q, k, part);
    hipLaunchKernelGGL(colsum_fin, dim3(4, 8), dim3(256), 0, stream, part, sums);
    hipLaunchKernelGGL(proj_sums, dim3(64, 2), dim3(256), 0, stream, sums, Wq, bq, Wk, bk, SQK);
    hipLaunchKernelGGL(stats_topk, dim3(1), dim3(256), 0, stream, SQK, dly, wts);

    // weight prep: Wo->f16, WvT->f16; Wc = Wo @ Wv (f16 out); bc = Wo@bv + bo
    hipLaunchKernelGGL(prep_w, dim3(32, 32, 2), dim3(32, 8), 0, stream, Wo, Wv, Wof, WvTf);
    hipLaunchKernelGGL((gemm_f16<64, true>), dim3(256), dim3(256), 0, stream,
                       Wof, WvTf, (float*)nullptr, Wcf, (const float*)nullptr,
                       1024, 1024, 16);
    hipLaunchKernelGGL(bcvec_k, dim3(64), dim3(256), 0, stream, Wo, bv, bo, bc);

    // gather on v (commutes with output projection) -> f16
    hipLaunchKernelGGL(gather_v, dim3(32, 16, 4), dim3(256), 0, stream, v, dly, wts, Vf);

    // out = Vagg @ Wc^T + bc  (16384 x 1024 x 1024), single f16 MFMA
    hipLaunchKernelGGL((gemm_f16<128, false>), dim3(1024), dim3(256), 0, stream,
                       Vf, Wcf, out, (unsigned short*)nullptr, bc, 1024, 1024, 8);
}

// Round 6
// 161.392 us; speedup vs baseline: 1.8595x; 1.1081x over previous
//
#include <hip/hip_runtime.h>
#include <hip/hip_bf16.h>

#define Bn 4
#define Ln 4096
#define Dn 1024
#define Hn 16
#define KSEL 41

typedef __attribute__((ext_vector_type(8))) _Float16 f16x8;
typedef __attribute__((ext_vector_type(4))) float f32x4;

// ---------- f32 -> f16 bits (RNE via hardware cvt) ----------
__device__ __forceinline__ unsigned short f2h(float f) {
    union { _Float16 h; unsigned short u; } c;
    c.h = (_Float16)f;
    return c.u;
}

// ---------- async global->LDS, 16B per lane ----------
__device__ __forceinline__ void gl2lds16(const unsigned short* g, unsigned short* l) {
    __builtin_amdgcn_global_load_lds(
        (const __attribute__((address_space(1))) unsigned int*)(uintptr_t)g,
        (__attribute__((address_space(3))) unsigned int*)(uintptr_t)l,
        16, 0, 0);
}

// ---------------- column sums of q and k ----------------
__global__ void colsum_part(const float* __restrict__ q, const float* __restrict__ k,
                            float* __restrict__ part) {
    int tb = blockIdx.y; int tensor = tb >> 2, b = tb & 3;
    const float4* src = (const float4*)((tensor ? k : q) + (size_t)b * Ln * Dn);
    int d4 = threadIdx.x;
    int t0 = blockIdx.x * 128;
    float sx = 0.f, sy = 0.f, sz = 0.f, sw = 0.f;
    for (int i = 0; i < 128; ++i) {
        float4 v = src[(size_t)(t0 + i) * 256 + d4];
        sx += v.x; sy += v.y; sz += v.z; sw += v.w;
    }
    float4 o; o.x = sx; o.y = sy; o.z = sz; o.w = sw;
    ((float4*)part)[((size_t)tb * 32 + blockIdx.x) * 256 + d4] = o;
}

__global__ void colsum_fin(const float* __restrict__ part, float* __restrict__ sums) {
    int tb = blockIdx.y; int d = blockIdx.x * 256 + threadIdx.x;
    float s = 0.f;
    for (int i = 0; i < 32; ++i) s += part[((size_t)tb * 32 + i) * 1024 + d];
    sums[(size_t)tb * 1024 + d] = s;
}

// ---------------- SQ/SK = colsum @ W^T + L*bias ----------------
__global__ void proj_sums(const float* __restrict__ sums,
                          const float* __restrict__ Wq, const float* __restrict__ bq,
                          const float* __restrict__ Wk, const float* __restrict__ bk,
                          float* __restrict__ SQK) {
    int t = blockIdx.y;
    const float* W    = t ? Wk : Wq;
    const float* bias = t ? bk : bq;
    const float* sv   = sums + (size_t)t * 4 * 1024;
    __shared__ float s_sv[4 * 1024];
    for (int i = threadIdx.x; i < 4 * 1024; i += 256) s_sv[i] = sv[i];
    __syncthreads();
    int wave = threadIdx.x >> 6, lane = threadIdx.x & 63;
    for (int rr = 0; rr < 4; ++rr) {
        int j = blockIdx.x * 16 + rr * 4 + wave;
        float p[4] = {0.f, 0.f, 0.f, 0.f};
        for (int c = 0; c < 4; ++c) {
            float4 wv = *(const float4*)(W + (size_t)j * 1024 + c * 256 + lane * 4);
            #pragma unroll
            for (int b = 0; b < 4; ++b) {
                float4 s = *(const float4*)(s_sv + b * 1024 + c * 256 + lane * 4);
                p[b] += wv.x * s.x + wv.y * s.y + wv.z * s.z + wv.w * s.w;
            }
        }
        #pragma unroll
        for (int b = 0; b < 4; ++b)
            for (int off = 1; off < 64; off <<= 1) p[b] += __shfl_xor(p[b], off);
        if (lane == 0) {
            float bb = bias[j] * (float)Ln;
            #pragma unroll
            for (int b = 0; b < 4; ++b) SQK[((size_t)t * 4 + b) * 1024 + j] = p[b] + bb;
        }
    }
}

// ---------------- fused mean_value + top-41 + softmax + dense tap table ----------------
__global__ void stats_topk(const float* __restrict__ SQK, int* __restrict__ dly,
                           float* __restrict__ gp) {
    __shared__ float s_mv[4][64];
    __shared__ float mab[64];
    __shared__ float selv[4][KSEL];
    __shared__ int   s_dly[KSEL];
    int tid = threadIdx.x; int b = tid >> 6, c = tid & 63;
    const float* SQ = SQK; const float* SK = SQK + 4 * 1024;
    float s = 0.f;
    for (int h = 0; h < Hn; ++h)
        s += SQ[(size_t)b * 1024 + h * 64 + c] * SK[(size_t)b * 1024 + h * 64 + c];
    s_mv[b][c] = s * (1.0f / ((float)Hn * (float)Ln));
    __syncthreads();
    if (tid < 64) mab[c] = (s_mv[0][c] + s_mv[1][c] + s_mv[2][c] + s_mv[3][c]) * 0.25f;
    __syncthreads();
    if (tid < 64) {
        float my = mab[c];
        int rank = 0;
        for (int j = 0; j < 64; ++j) {
            float vj = mab[j];
            rank += (vj > my) || (vj == my && j < c);
        }
        if (rank < KSEL) {
            s_dly[rank] = c;
            dly[rank] = c;
            selv[0][rank] = s_mv[0][c]; selv[1][rank] = s_mv[1][c];
            selv[2][rank] = s_mv[2][c]; selv[3][rank] = s_mv[3][c];
        }
    }
    __syncthreads();
    // zero the dense table: 4 batches x 64 delays
    if (tid < 256) gp[tid] = 0.f;
    __syncthreads();
    if (tid < 4) {
        float mx = -1e30f;
        for (int i = 0; i < KSEL; ++i) mx = fmaxf(mx, selv[tid][i]);
        float ss = 0.f;
        for (int i = 0; i < KSEL; ++i) ss += expf(selv[tid][i] - mx);
        float inv = 1.0f / ss;
        for (int i = 0; i < KSEL; ++i)
            gp[tid * 64 + s_dly[i]] = expf(selv[tid][i] - mx) * inv;
    }
}

// ---------------- weight prep: z=0 Wo->f16 straight; z=1 Wv->transpose->f16 ----------------
__global__ void prep_w(const float* __restrict__ Wo, const float* __restrict__ Wv,
                       unsigned short* __restrict__ Wof, unsigned short* __restrict__ WvTf) {
    int bx = blockIdx.x * 32, by = blockIdx.y * 32;
    int x = threadIdx.x, y0 = threadIdx.y;
    if (blockIdx.z == 0) {
        for (int i = 0; i < 32; i += 8) {
            size_t idx = (size_t)(by + y0 + i) * 1024 + bx + x;
            Wof[idx] = f2h(Wo[idx]);
        }
    } else {
        __shared__ float t[32][33];
        for (int i = 0; i < 32; i += 8)
            t[y0 + i][x] = Wv[(size_t)(by + y0 + i) * 1024 + bx + x];
        __syncthreads();
        for (int i = 0; i < 32; i += 8)
            WvTf[(size_t)(bx + y0 + i) * 1024 + by + x] = f2h(t[x][y0 + i]);
    }
}

// ---------------- bc = Wo @ bv + bo (fp32) ----------------
__global__ void bcvec_k(const float* __restrict__ Wo, const float* __restrict__ bv,
                        const float* __restrict__ bo, float* __restrict__ bc) {
    __shared__ float s_bv[1024];
    for (int i = threadIdx.x; i < 1024; i += 256) s_bv[i] = bv[i];
    __syncthreads();
    int wave = threadIdx.x >> 6, lane = threadIdx.x & 63;
    for (int rr = 0; rr < 4; ++rr) {
        int n = blockIdx.x * 16 + rr * 4 + wave;
        float p = 0.f;
        for (int c = 0; c < 4; ++c) {
            float4 wv = *(const float4*)(Wo + (size_t)n * 1024 + c * 256 + lane * 4);
            float4 s  = *(const float4*)(s_bv + c * 256 + lane * 4);
            p += wv.x * s.x + wv.y * s.y + wv.z * s.z + wv.w * s.w;
        }
        for (int off = 1; off < 64; off <<= 1) p += __shfl_xor(p, off);
        if (lane == 0) bc[n] = p + bo[n];
    }
}

// ---------------- gather as register-blocked dense 64-tap FIR -> f16 ----------------
// Vf[b,t,c] = f16( sum_{delta in [0,64)} g[b][delta] * v[b,(t+delta)%L,c] )
// Thread: 8 consecutive t-rows x 4 channels; reads each input row ONCE from LDS.
#define FT 128
#define FC 64
#define FW 64
__global__ __launch_bounds__(256) void gather_fir(const float* __restrict__ v,
                                                  const float* __restrict__ gp,
                                                  unsigned short* __restrict__ Vf) {
    __shared__ float S[FT + FW][FC];   // 192 x 64 x 4B = 48 KB, row stride 256B
    int b = blockIdx.z, c0 = blockIdx.y * FC, t0 = blockIdx.x * FT;
    const float* Vb = v + (size_t)b * Ln * Dn;
    for (int idx = threadIdx.x; idx < (FT + FW) * 16; idx += 256) {
        int r = idx >> 4, c4 = idx & 15;
        int gr = (t0 + r) & (Ln - 1);
        *(float4*)&S[r][c4 * 4] = *(const float4*)&Vb[(size_t)gr * Dn + c0 + c4 * 4];
    }
    // dense tap weights -> registers (all indices compile-time => VGPR-resident)
    float g[64];
    #pragma unroll
    for (int i = 0; i < 16; ++i)
        *(float4*)&g[i * 4] = ((const float4*)(gp + b * 64))[i];
    __syncthreads();
    int c4 = threadIdx.x & 15, rg = threadIdx.x >> 4;   // 16 row-groups of 8 t
    const int base = rg * 8;
    float4 acc[8];
    #pragma unroll
    for (int i = 0; i < 8; ++i) acc[i] = make_float4(0.f, 0.f, 0.f, 0.f);
    #pragma unroll
    for (int u = 0; u < FW + 7; ++u) {                  // 71 window rows, read once
        float4 x = *(const float4*)&S[base + u][c4 * 4];
        #pragma unroll
        for (int i = 0; i < 8; ++i) {
            if (i <= u && u - i < FW) {                 // compile-time predicate
                float w = g[u - i];
                acc[i].x += w * x.x; acc[i].y += w * x.y;
                acc[i].z += w * x.z; acc[i].w += w * x.w;
            }
        }
    }
    #pragma unroll
    for (int i = 0; i < 8; ++i) {
        size_t idx = ((size_t)b * Ln + t0 + base + i) * Dn + c0 + c4 * 4;
        ushort4 o;
        o.x = f2h(acc[i].x); o.y = f2h(acc[i].y);
        o.z = f2h(acc[i].z); o.w = f2h(acc[i].w);
        *(ushort4*)&Vf[idx] = o;
    }
}

// ---------------- f16 single-MFMA NT GEMM (m97 structure) ----------------
template <int BM, bool OUT_F16>
__global__ __launch_bounds__(256, 2) void gemm_f16(
    const unsigned short* __restrict__ A, const unsigned short* __restrict__ Bt,
    float* __restrict__ C, unsigned short* __restrict__ Cf,
    const float* __restrict__ bias,
    int N, int K, int nbx) {
    constexpr int FM = BM / 32;
    __shared__ unsigned short sA[BM * 32];
    __shared__ unsigned short sB[BM * 32];

    int nwg = gridDim.x;
    int bid = blockIdx.x;
    int swz = (bid % 8) * (nwg / 8) + bid / 8;   // nwg % 8 == 0 for our grids
    int by = swz / nbx, bx = swz % nbx;

    const int wave = threadIdx.x >> 6, lane = threadIdx.x & 63;
    const int lrow = lane & 15, lk = (lane >> 4) * 8;
    const int wr = wave >> 1, wc = wave & 1;

    f32x4 acc[FM][FM];
    #pragma unroll
    for (int i = 0; i < FM; ++i)
        #pragma unroll
        for (int j = 0; j < FM; ++j) acc[i][j] = (f32x4){0.f, 0.f, 0.f, 0.f};

    const int srow = lane >> 2;
    const int skq  = (lane & 3) * 8;

    for (int k0 = 0; k0 < K; k0 += 32) {
        #pragma unroll
        for (int j = 0; j < BM / 64; ++j) {
            int chunk = j * 4 + wave;
            int row = chunk * 16 + srow;
            gl2lds16(A  + (size_t)((by * BM) + row) * K + k0 + skq, sA + chunk * 512);
            gl2lds16(Bt + (size_t)((bx * BM) + row) * K + k0 + skq, sB + chunk * 512);
        }
        __syncthreads();
        f16x8 bfrag[FM];
        #pragma unroll
        for (int j = 0; j < FM; ++j) {
            int r = wc * (BM / 2) + j * 16 + lrow;
            bfrag[j] = *(const f16x8*)&sB[r * 32 + lk];
        }
        #pragma unroll
        for (int i = 0; i < FM; ++i) {
            int r = wr * (BM / 2) + i * 16 + lrow;
            f16x8 afrag = *(const f16x8*)&sA[r * 32 + lk];
            #pragma unroll
            for (int j = 0; j < FM; ++j)
                acc[i][j] = __builtin_amdgcn_mfma_f32_16x16x32_f16(afrag, bfrag[j], acc[i][j], 0, 0, 0);
        }
        __syncthreads();
    }
    #pragma unroll
    for (int i = 0; i < FM; ++i) {
        int r0 = by * BM + wr * (BM / 2) + i * 16 + (lane >> 4) * 4;
        #pragma unroll
        for (int j = 0; j < FM; ++j) {
            int c = bx * BM + wc * (BM / 2) + j * 16 + (lane & 15);
            float bb = OUT_F16 ? 0.f : bias[c];
            #pragma unroll
            for (int r = 0; r < 4; ++r) {
                size_t idx = (size_t)(r0 + r) * N + c;
                if (OUT_F16) Cf[idx] = f2h(acc[i][j][r]);
                else         C[idx]  = acc[i][j][r] + bb;
            }
        }
    }
}

extern "C" void kernel_launch(void* const* d_in, const int* in_sizes, int n_in,
                              void* d_out, int out_size, void* d_ws, size_t ws_size,
                              hipStream_t stream) {
    const float* q  = (const float*)d_in[0];
    const float* k  = (const float*)d_in[1];
    const float* v  = (const float*)d_in[2];
    const float* Wq = (const float*)d_in[3];
    const float* bq = (const float*)d_in[4];
    const float* Wk = (const float*)d_in[5];
    const float* bk = (const float*)d_in[6];
    const float* Wv = (const float*)d_in[7];
    const float* bv = (const float*)d_in[8];
    const float* Wo = (const float*)d_in[9];
    const float* bo = (const float*)d_in[10];
    float* out = (float*)d_out;
    float* ws  = (float*)d_ws;

    unsigned short* Vf    = (unsigned short*)ws;        // 16777216 ushort (32 MB)
    unsigned short* Wof   = Vf + 16777216;              // 1048576
    unsigned short* WvTf  = Wof + 1048576;              // 1048576
    unsigned short* Wcf   = WvTf + 1048576;             // 1048576
    float* part = (float*)(Wcf + 1048576);              // 262144 floats
    float* sums = part + 262144;                        // 8192
    float* SQK  = sums + 8192;                          // 8192
    float* gp   = SQK + 8192;                           // 256 (4 x 64 dense taps)
    float* bc   = gp + 256;                             // 1024
    int*   dly  = (int*)(bc + 1024);                    // 64

    // correlation-stats chain -> dense tap table gp
    hipLaunchKernelGGL(colsum_part, dim3(32, 8), dim3(256), 0, stream, q, k, part);
    hipLaunchKernelGGL(colsum_fin, dim3(4, 8), dim3(256), 0, stream, part, sums);
    hipLaunchKernelGGL(proj_sums, dim3(64, 2), dim3(256), 0, stream, sums, Wq, bq, Wk, bk, SQK);
    hipLaunchKernelGGL(stats_topk, dim3(1), dim3(256), 0, stream, SQK, dly, gp);

    // weight prep: Wo->f16, WvT->f16; Wc = Wo @ Wv (f16 out); bc = Wo@bv + bo
    hipLaunchKernelGGL(prep_w, dim3(32, 32, 2), dim3(32, 8), 0, stream, Wo, Wv, Wof, WvTf);
    hipLaunchKernelGGL((gemm_f16<64, true>), dim3(256), dim3(256), 0, stream,
                       Wof, WvTf, (float*)nullptr, Wcf, (const float*)nullptr,
                       1024, 1024, 16);
    hipLaunchKernelGGL(bcvec_k, dim3(64), dim3(256), 0, stream, Wo, bv, bo, bc);

    // gather on v as dense 64-tap FIR -> f16
    hipLaunchKernelGGL(gather_fir, dim3(32, 16, 4), dim3(256), 0, stream, v, gp, Vf);

    // out = Vagg @ Wc^T + bc  (16384 x 1024 x 1024), single f16 MFMA
    hipLaunchKernelGGL((gemm_f16<128, false>), dim3(1024), dim3(256), 0, stream,
                       Vf, Wcf, out, (unsigned short*)nullptr, bc, 1024, 1024, 8);
}

// Round 7
// 149.746 us; speedup vs baseline: 2.0042x; 1.0778x over previous
//
#include <hip/hip_runtime.h>
#include <hip/hip_bf16.h>

#define Bn 4
#define Ln 4096
#define Dn 1024
#define Hn 16
#define KSEL 41

typedef __attribute__((ext_vector_type(8))) _Float16 f16x8;
typedef __attribute__((ext_vector_type(4))) float f32x4;

// ---------- f32 -> f16 bits (RNE via hardware cvt) ----------
__device__ __forceinline__ unsigned short f2h(float f) {
    union { _Float16 h; unsigned short u; } c;
    c.h = (_Float16)f;
    return c.u;
}

// ---------- async global->LDS, 16B per lane ----------
__device__ __forceinline__ void gl2lds16(const unsigned short* g, unsigned short* l) {
    __builtin_amdgcn_global_load_lds(
        (const __attribute__((address_space(1))) unsigned int*)(uintptr_t)g,
        (__attribute__((address_space(3))) unsigned int*)(uintptr_t)l,
        16, 0, 0);
}
__device__ __forceinline__ void gl2lds16f(const float* g, float* l) {
    __builtin_amdgcn_global_load_lds(
        (const __attribute__((address_space(1))) unsigned int*)(uintptr_t)g,
        (__attribute__((address_space(3))) unsigned int*)(uintptr_t)l,
        16, 0, 0);
}

// ---------------- column sums of q and k ----------------
__global__ void colsum_part(const float* __restrict__ q, const float* __restrict__ k,
                            float* __restrict__ part) {
    int tb = blockIdx.y; int tensor = tb >> 2, b = tb & 3;
    const float4* src = (const float4*)((tensor ? k : q) + (size_t)b * Ln * Dn);
    int d4 = threadIdx.x;
    int t0 = blockIdx.x * 128;
    float sx = 0.f, sy = 0.f, sz = 0.f, sw = 0.f;
    for (int i = 0; i < 128; ++i) {
        float4 v = src[(size_t)(t0 + i) * 256 + d4];
        sx += v.x; sy += v.y; sz += v.z; sw += v.w;
    }
    float4 o; o.x = sx; o.y = sy; o.z = sz; o.w = sw;
    ((float4*)part)[((size_t)tb * 32 + blockIdx.x) * 256 + d4] = o;
}

__global__ void colsum_fin(const float* __restrict__ part, float* __restrict__ sums) {
    int tb = blockIdx.y; int d = blockIdx.x * 256 + threadIdx.x;
    float s = 0.f;
    for (int i = 0; i < 32; ++i) s += part[((size_t)tb * 32 + i) * 1024 + d];
    sums[(size_t)tb * 1024 + d] = s;
}

// ---------------- SQ/SK = colsum @ W^T + L*bias ----------------
__global__ void proj_sums(const float* __restrict__ sums,
                          const float* __restrict__ Wq, const float* __restrict__ bq,
                          const float* __restrict__ Wk, const float* __restrict__ bk,
                          float* __restrict__ SQK) {
    int t = blockIdx.y;
    const float* W    = t ? Wk : Wq;
    const float* bias = t ? bk : bq;
    const float* sv   = sums + (size_t)t * 4 * 1024;
    __shared__ float s_sv[4 * 1024];
    for (int i = threadIdx.x; i < 4 * 1024; i += 256) s_sv[i] = sv[i];
    __syncthreads();
    int wave = threadIdx.x >> 6, lane = threadIdx.x & 63;
    for (int rr = 0; rr < 4; ++rr) {
        int j = blockIdx.x * 16 + rr * 4 + wave;
        float p[4] = {0.f, 0.f, 0.f, 0.f};
        for (int c = 0; c < 4; ++c) {
            float4 wv = *(const float4*)(W + (size_t)j * 1024 + c * 256 + lane * 4);
            #pragma unroll
            for (int b = 0; b < 4; ++b) {
                float4 s = *(const float4*)(s_sv + b * 1024 + c * 256 + lane * 4);
                p[b] += wv.x * s.x + wv.y * s.y + wv.z * s.z + wv.w * s.w;
            }
        }
        #pragma unroll
        for (int b = 0; b < 4; ++b)
            for (int off = 1; off < 64; off <<= 1) p[b] += __shfl_xor(p[b], off);
        if (lane == 0) {
            float bb = bias[j] * (float)Ln;
            #pragma unroll
            for (int b = 0; b < 4; ++b) SQK[((size_t)t * 4 + b) * 1024 + j] = p[b] + bb;
        }
    }
}

// ---------------- fused mean_value + top-41 + softmax + dense tap table ----------------
__global__ void stats_topk(const float* __restrict__ SQK, int* __restrict__ dly,
                           float* __restrict__ gp) {
    __shared__ float s_mv[4][64];
    __shared__ float mab[64];
    __shared__ float selv[4][KSEL];
    __shared__ int   s_dly[KSEL];
    int tid = threadIdx.x; int b = tid >> 6, c = tid & 63;
    const float* SQ = SQK; const float* SK = SQK + 4 * 1024;
    float s = 0.f;
    for (int h = 0; h < Hn; ++h)
        s += SQ[(size_t)b * 1024 + h * 64 + c] * SK[(size_t)b * 1024 + h * 64 + c];
    s_mv[b][c] = s * (1.0f / ((float)Hn * (float)Ln));
    __syncthreads();
    if (tid < 64) mab[c] = (s_mv[0][c] + s_mv[1][c] + s_mv[2][c] + s_mv[3][c]) * 0.25f;
    __syncthreads();
    if (tid < 64) {
        float my = mab[c];
        int rank = 0;
        for (int j = 0; j < 64; ++j) {
            float vj = mab[j];
            rank += (vj > my) || (vj == my && j < c);
        }
        if (rank < KSEL) {
            s_dly[rank] = c;
            dly[rank] = c;
            selv[0][rank] = s_mv[0][c]; selv[1][rank] = s_mv[1][c];
            selv[2][rank] = s_mv[2][c]; selv[3][rank] = s_mv[3][c];
        }
    }
    __syncthreads();
    // zero the dense table: 4 batches x 64 delays
    if (tid < 256) gp[tid] = 0.f;
    __syncthreads();
    if (tid < 4) {
        float mx = -1e30f;
        for (int i = 0; i < KSEL; ++i) mx = fmaxf(mx, selv[tid][i]);
        float ss = 0.f;
        for (int i = 0; i < KSEL; ++i) ss += expf(selv[tid][i] - mx);
        float inv = 1.0f / ss;
        for (int i = 0; i < KSEL; ++i)
            gp[tid * 64 + s_dly[i]] = expf(selv[tid][i] - mx) * inv;
    }
}

// ---------------- weight prep: z=0 Wo->f16 straight; z=1 Wv->transpose->f16 ----------------
__global__ void prep_w(const float* __restrict__ Wo, const float* __restrict__ Wv,
                       unsigned short* __restrict__ Wof, unsigned short* __restrict__ WvTf) {
    int bx = blockIdx.x * 32, by = blockIdx.y * 32;
    int x = threadIdx.x, y0 = threadIdx.y;
    if (blockIdx.z == 0) {
        for (int i = 0; i < 32; i += 8) {
            size_t idx = (size_t)(by + y0 + i) * 1024 + bx + x;
            Wof[idx] = f2h(Wo[idx]);
        }
    } else {
        __shared__ float t[32][33];
        for (int i = 0; i < 32; i += 8)
            t[y0 + i][x] = Wv[(size_t)(by + y0 + i) * 1024 + bx + x];
        __syncthreads();
        for (int i = 0; i < 32; i += 8)
            WvTf[(size_t)(bx + y0 + i) * 1024 + by + x] = f2h(t[x][y0 + i]);
    }
}

// ---------------- bc = Wo @ bv + bo (fp32) ----------------
__global__ void bcvec_k(const float* __restrict__ Wo, const float* __restrict__ bv,
                        const float* __restrict__ bo, float* __restrict__ bc) {
    __shared__ float s_bv[1024];
    for (int i = threadIdx.x; i < 1024; i += 256) s_bv[i] = bv[i];
    __syncthreads();
    int wave = threadIdx.x >> 6, lane = threadIdx.x & 63;
    for (int rr = 0; rr < 4; ++rr) {
        int n = blockIdx.x * 16 + rr * 4 + wave;
        float p = 0.f;
        for (int c = 0; c < 4; ++c) {
            float4 wv = *(const float4*)(Wo + (size_t)n * 1024 + c * 256 + lane * 4);
            float4 s  = *(const float4*)(s_bv + c * 256 + lane * 4);
            p += wv.x * s.x + wv.y * s.y + wv.z * s.z + wv.w * s.w;
        }
        for (int off = 1; off < 64; off <<= 1) p += __shfl_xor(p, off);
        if (lane == 0) bc[n] = p + bo[n];
    }
}

// ---------------- gather as dense 64-tap FIR, 2 chunks of 32 taps -> f16 ----------------
// Vf[b,t,c] = f16( sum_{delta in [0,64)} g[b][delta] * v[b,(t+delta)%L,c] )
// Tap-chunking keeps the live register set at ~85 VGPR (32 gc + 32 acc) so nothing
// spills to scratch (round-6 lesson: g[64]+acc exceeded the allocator's budget at
// VGPR_Count=76 -> scratch traffic -> 61us latency-bound).
#define FT 128
#define FC 64
#define FW 64
__global__ __launch_bounds__(256) void gather_fir(const float* __restrict__ v,
                                                  const float* __restrict__ gp,
                                                  unsigned short* __restrict__ Vf) {
    __shared__ float S[(FT + FW) * FC];   // 192 rows x 64 ch = 48 KB, row stride 256B
    int b = blockIdx.z, c0 = blockIdx.y * FC, t0 = blockIdx.x * FT;
    const float* Vb = v + (size_t)b * Ln * Dn;
    // async staging: 12 x (256 lanes x 16B), LDS dest linear in thread index
    #pragma unroll
    for (int it = 0; it < 12; ++it) {
        int idx = it * 256 + threadIdx.x;           // 16B slot
        int r = idx >> 4, cc = idx & 15;
        int gr = (t0 + r) & (Ln - 1);
        gl2lds16f(Vb + (size_t)gr * Dn + c0 + cc * 4, S + idx * 4);
    }
    __syncthreads();
    int c4 = threadIdx.x & 15, rg = threadIdx.x >> 4;   // 16 row-groups of 8 t
    const int base = rg * 8;
    float4 acc[8];
    #pragma unroll
    for (int i = 0; i < 8; ++i) acc[i] = make_float4(0.f, 0.f, 0.f, 0.f);
    #pragma unroll
    for (int tc = 0; tc < 2; ++tc) {
        // 32 tap weights for this chunk -> registers (all-static indices)
        float gc[32];
        #pragma unroll
        for (int j = 0; j < 8; ++j) {
            float4 gv = ((const float4*)(gp + b * 64 + tc * 32))[j];
            gc[j * 4 + 0] = gv.x; gc[j * 4 + 1] = gv.y;
            gc[j * 4 + 2] = gv.z; gc[j * 4 + 3] = gv.w;
        }
        #pragma unroll
        for (int w = 0; w < 39; ++w) {                  // 32 taps + 8 rows - 1
            float4 x = *(const float4*)&S[(base + tc * 32 + w) * FC + c4 * 4];
            #pragma unroll
            for (int i = 0; i < 8; ++i) {
                int j = w - i;                          // compile-time
                if (j >= 0 && j < 32) {
                    float wt = gc[j];
                    acc[i].x += wt * x.x; acc[i].y += wt * x.y;
                    acc[i].z += wt * x.z; acc[i].w += wt * x.w;
                }
            }
        }
    }
    #pragma unroll
    for (int i = 0; i < 8; ++i) {
        size_t idx = ((size_t)b * Ln + t0 + base + i) * Dn + c0 + c4 * 4;
        ushort4 o;
        o.x = f2h(acc[i].x); o.y = f2h(acc[i].y);
        o.z = f2h(acc[i].z); o.w = f2h(acc[i].w);
        *(ushort4*)&Vf[idx] = o;
    }
}

// ---------------- f16 single-MFMA NT GEMM (m97 structure) ----------------
template <int BM, bool OUT_F16>
__global__ __launch_bounds__(256, 2) void gemm_f16(
    const unsigned short* __restrict__ A, const unsigned short* __restrict__ Bt,
    float* __restrict__ C, unsigned short* __restrict__ Cf,
    const float* __restrict__ bias,
    int N, int K, int nbx) {
    constexpr int FM = BM / 32;
    __shared__ unsigned short sA[BM * 32];
    __shared__ unsigned short sB[BM * 32];

    int nwg = gridDim.x;
    int bid = blockIdx.x;
    int swz = (bid % 8) * (nwg / 8) + bid / 8;   // nwg % 8 == 0 for our grids
    int by = swz / nbx, bx = swz % nbx;

    const int wave = threadIdx.x >> 6, lane = threadIdx.x & 63;
    const int lrow = lane & 15, lk = (lane >> 4) * 8;
    const int wr = wave >> 1, wc = wave & 1;

    f32x4 acc[FM][FM];
    #pragma unroll
    for (int i = 0; i < FM; ++i)
        #pragma unroll
        for (int j = 0; j < FM; ++j) acc[i][j] = (f32x4){0.f, 0.f, 0.f, 0.f};

    const int srow = lane >> 2;
    const int skq  = (lane & 3) * 8;

    for (int k0 = 0; k0 < K; k0 += 32) {
        #pragma unroll
        for (int j = 0; j < BM / 64; ++j) {
            int chunk = j * 4 + wave;
            int row = chunk * 16 + srow;
            gl2lds16(A  + (size_t)((by * BM) + row) * K + k0 + skq, sA + chunk * 512);
            gl2lds16(Bt + (size_t)((bx * BM) + row) * K + k0 + skq, sB + chunk * 512);
        }
        __syncthreads();
        f16x8 bfrag[FM];
        #pragma unroll
        for (int j = 0; j < FM; ++j) {
            int r = wc * (BM / 2) + j * 16 + lrow;
            bfrag[j] = *(const f16x8*)&sB[r * 32 + lk];
        }
        #pragma unroll
        for (int i = 0; i < FM; ++i) {
            int r = wr * (BM / 2) + i * 16 + lrow;
            f16x8 afrag = *(const f16x8*)&sA[r * 32 + lk];
            #pragma unroll
            for (int j = 0; j < FM; ++j)
                acc[i][j] = __builtin_amdgcn_mfma_f32_16x16x32_f16(afrag, bfrag[j], acc[i][j], 0, 0, 0);
        }
        __syncthreads();
    }
    #pragma unroll
    for (int i = 0; i < FM; ++i) {
        int r0 = by * BM + wr * (BM / 2) + i * 16 + (lane >> 4) * 4;
        #pragma unroll
        for (int j = 0; j < FM; ++j) {
            int c = bx * BM + wc * (BM / 2) + j * 16 + (lane & 15);
            float bb = OUT_F16 ? 0.f : bias[c];
            #pragma unroll
            for (int r = 0; r < 4; ++r) {
                size_t idx = (size_t)(r0 + r) * N + c;
                if (OUT_F16) Cf[idx] = f2h(acc[i][j][r]);
                else         C[idx]  = acc[i][j][r] + bb;
            }
        }
    }
}

extern "C" void kernel_launch(void* const* d_in, const int* in_sizes, int n_in,
                              void* d_out, int out_size, void* d_ws, size_t ws_size,
                              hipStream_t stream) {
    const float* q  = (const float*)d_in[0];
    const float* k  = (const float*)d_in[1];
    const float* v  = (const float*)d_in[2];
    const float* Wq = (const float*)d_in[3];
    const float* bq = (const float*)d_in[4];
    const float* Wk = (const float*)d_in[5];
    const float* bk = (const float*)d_in[6];
    const float* Wv = (const float*)d_in[7];
    const float* bv = (const float*)d_in[8];
    const float* Wo = (const float*)d_in[9];
    const float* bo = (const float*)d_in[10];
    float* out = (float*)d_out;
    float* ws  = (float*)d_ws;

    unsigned short* Vf    = (unsigned short*)ws;        // 16777216 ushort (32 MB)
    unsigned short* Wof   = Vf + 16777216;              // 1048576
    unsigned short* WvTf  = Wof + 1048576;              // 1048576
    unsigned short* Wcf   = WvTf + 1048576;             // 1048576
    float* part = (float*)(Wcf + 1048576);              // 262144 floats
    float* sums = part + 262144;                        // 8192
    float* SQK  = sums + 8192;                          // 8192
    float* gp   = SQK + 8192;                           // 256 (4 x 64 dense taps)
    float* bc   = gp + 256;                             // 1024
    int*   dly  = (int*)(bc + 1024);                    // 64

    // correlation-stats chain -> dense tap table gp
    hipLaunchKernelGGL(colsum_part, dim3(32, 8), dim3(256), 0, stream, q, k, part);
    hipLaunchKernelGGL(colsum_fin, dim3(4, 8), dim3(256), 0, stream, part, sums);
    hipLaunchKernelGGL(proj_sums, dim3(64, 2), dim3(256), 0, stream, sums, Wq, bq, Wk, bk, SQK);
    hipLaunchKernelGGL(stats_topk, dim3(1), dim3(256), 0, stream, SQK, dly, gp);

    // weight prep: Wo->f16, WvT->f16; Wc = Wo @ Wv (f16 out); bc = Wo@bv + bo
    hipLaunchKernelGGL(prep_w, dim3(32, 32, 2), dim3(32, 8), 0, stream, Wo, Wv, Wof, WvTf);
    hipLaunchKernelGGL((gemm_f16<64, true>), dim3(256), dim3(256), 0, stream,
                       Wof, WvTf, (float*)nullptr, Wcf, (const float*)nullptr,
                       1024, 1024, 16);
    hipLaunchKernelGGL(bcvec_k, dim3(64), dim3(256), 0, stream, Wo, bv, bo, bc);

    // gather on v as dense 64-tap FIR (2x32-tap chunks) -> f16
    hipLaunchKernelGGL(gather_fir, dim3(32, 16, 4), dim3(256), 0, stream, v, gp, Vf);

    // out = Vagg @ Wc^T + bc  (16384 x 1024 x 1024), single f16 MFMA
    hipLaunchKernelGGL((gemm_f16<128, false>), dim3(1024), dim3(256), 0, stream,
                       Vf, Wcf, out, (unsigned short*)nullptr, bc, 1024, 1024, 8);
}